// Round 10
// baseline (308.093 us; speedup 1.0000x reference)
//
#include <hip/hip_runtime.h>
#include <math.h>

#define NN   50000
#define NE   800000
#define NG   500
#define FIN  80
#define FOUT 40
#define HH   20
#define NC   5
#define NREP 4

// -------- workspace layout (float offsets) --------
#define OFF_DEGR   0               // f32[4][NN]
#define OFF_CNTR   200000          // u32[4][NN]
#define OFF_POOLED 400000          // f32[NG*FOUT]
#define OFF_DINV   420000          // f32[NN]
#define OFF_CNT    470000          // u32[NN] (cnt -> cursor)
#define OFF_PRE    520000
#define OFF_SEQ    530000
#define OFF_ROWPTR 540000          // u32[NN+1] (+pad)
#define OFF_ESRC   590004          // u32[NE]
#define OFF_ENORM  1390004         // f32[NE] (= reordered w)
#define OFF_Y      2190004         // bf16[NN*FOUT] = 4 MB

// fast tanh: 1 - 2/(exp2(2*log2e*x)+1); exact saturation at +-inf
__device__ __forceinline__ float tanh_fast(float x) {
    float e;
    asm("v_exp_f32 %0, %1" : "=v"(e) : "v"(x * 2.8853900817779268f));
    float r;
    asm("v_rcp_f32 %0, %1" : "=v"(r) : "v"(e + 1.0f));
    return fmaf(-2.0f, r, 1.0f);
}

__device__ __forceinline__ float bcast_lane(float v, int k) {
    return __uint_as_float(__builtin_amdgcn_readlane(__float_as_uint(v), k));
}

__device__ __forceinline__ unsigned short bf16_rn(float f) {
    unsigned u = __float_as_uint(f);
    return (unsigned short)((u + 0x7fffu + ((u >> 16) & 1u)) >> 16);
}
__device__ __forceinline__ float bf16_to_f32(unsigned short h) {
    return __uint_as_float((unsigned)h << 16);
}

// ---- degR[r][src] += w ; cntR[r][dst] += 1  (r = blockIdx&3: 4x less same-address contention) ----
__global__ void k_degcnt(const int* __restrict__ ei, const float* __restrict__ w,
                         float* __restrict__ degR, unsigned int* __restrict__ cntR) {
    int e = blockIdx.x * 256 + threadIdx.x;
    int r = blockIdx.x & (NREP - 1);
    if (e < NE) {
        atomicAdd(&degR[r * NN + ei[e]], w[e]);
        atomicAdd(&cntR[r * NN + ei[NE + e]], 1u);
    }
}

// ---- reduce replicas: dinv[n] = rsqrt(sum degR), cnt[n] = sum cntR ----
__global__ void k_reduce(const float* __restrict__ degR, const unsigned int* __restrict__ cntR,
                         float* __restrict__ dinv, unsigned int* __restrict__ cnt) {
    int n = blockIdx.x * 256 + threadIdx.x;
    if (n >= NN) return;
    float d = degR[n] + degR[NN + n] + degR[2 * NN + n] + degR[3 * NN + n];
    dinv[n] = (d > 0.f) ? rsqrtf(d) : 0.f;
    cnt[n] = cntR[n] + cntR[NN + n] + cntR[2 * NN + n] + cntR[3 * NN + n];
}

// ---- exclusive scan of cnt -> rowptr; cnt := exclusive prefix (fill cursor) ----
__global__ void k_scanptr(unsigned int* __restrict__ cnt, unsigned int* __restrict__ rowptr) {
    __shared__ unsigned int tot[1024];
    int tid = threadIdx.x;
    bool act = tid < 1000;
    int beg = tid * 50;
    unsigned int vals[50];
    if (act) {
        const uint2* c2 = reinterpret_cast<const uint2*>(cnt + beg);
        #pragma unroll
        for (int j = 0; j < 25; ++j) {
            uint2 v = c2[j];
            vals[j * 2 + 0] = v.x;
            vals[j * 2 + 1] = v.y;
        }
    }
    unsigned int s = 0;
    if (act) {
        #pragma unroll
        for (int j = 0; j < 50; ++j) s += vals[j];
    }
    tot[tid] = s;
    __syncthreads();
    for (int off = 1; off < 1024; off <<= 1) {
        unsigned int t = (tid >= off) ? tot[tid - off] : 0u;
        __syncthreads();
        tot[tid] += t;
        __syncthreads();
    }
    unsigned int base = (tid > 0) ? tot[tid - 1] : 0u;
    if (act) {
        #pragma unroll
        for (int j = 0; j < 50; ++j) {
            unsigned int v = vals[j];
            vals[j] = base;
            base += v;
        }
        uint2* r2 = reinterpret_cast<uint2*>(rowptr + beg);
        uint2* cw = reinterpret_cast<uint2*>(cnt + beg);
        #pragma unroll
        for (int j = 0; j < 25; ++j) {
            uint2 o = make_uint2(vals[j * 2 + 0], vals[j * 2 + 1]);
            r2[j] = o;
            cw[j] = o;
        }
    }
    if (tid == 1023) rowptr[NN] = tot[1023];
}

// ---- y' = bf16(dinv[n] * (x @ W1)) : thread per (node, 4-col chunk) ----
__global__ void k_y(const float* __restrict__ x, const float* __restrict__ W1,
                    const float* __restrict__ dinv, unsigned short* __restrict__ y) {
    int gid = blockIdx.x * 256 + threadIdx.x;
    if (gid >= NN * 10) return;
    int n = gid / 10;
    int c = gid % 10;
    const float* xr = x + (size_t)n * FIN;
    float a0 = 0.f, a1 = 0.f, a2 = 0.f, a3 = 0.f;
    #pragma unroll 8
    for (int f = 0; f < FIN; ++f) {
        float xf = xr[f];
        const float4 wv = *reinterpret_cast<const float4*>(W1 + f * FOUT + c * 4);
        a0 = fmaf(xf, wv.x, a0); a1 = fmaf(xf, wv.y, a1);
        a2 = fmaf(xf, wv.z, a2); a3 = fmaf(xf, wv.w, a3);
    }
    float di = dinv[n];
    ushort4 o;
    o.x = bf16_rn(a0 * di); o.y = bf16_rn(a1 * di);
    o.z = bf16_rn(a2 * di); o.w = bf16_rn(a3 * di);
    *reinterpret_cast<ushort4*>(y + (size_t)gid * 4) = o;
}

// ---- fill CSR records: esrc[pos]=src, enorm[pos]=w[e]  (no deg reads) ----
__global__ void k_fill(const int* __restrict__ ei, const float* __restrict__ w,
                       unsigned int* __restrict__ cursor,
                       unsigned int* __restrict__ esrc, float* __restrict__ enorm) {
    int e = blockIdx.x * 256 + threadIdx.x;
    if (e >= NE) return;
    int s = ei[e];
    int d = ei[NE + e];
    unsigned int pos = atomicAdd(&cursor[d], 1u);
    esrc[pos] = (unsigned int)s;
    enorm[pos] = w[e];
}

// ---- gather z = sum w*y'[src]; h = relu(x@W0 + b - dinv[n]*z);
//      per-block LDS pool accumulation, then flush to global pooled ----
__global__ void k_gather_h(const unsigned int* __restrict__ rowptr,
                           const unsigned int* __restrict__ esrc,
                           const float* __restrict__ enorm,
                           const unsigned short* __restrict__ y,
                           const float* __restrict__ x,
                           const float* __restrict__ W0,
                           const float* __restrict__ bconv,
                           const float* __restrict__ dinv,
                           const int* __restrict__ batch,
                           float* __restrict__ pooled) {
    __shared__ float lpool[32 * FOUT];
    int tid = threadIdx.x;
    int b0 = blockIdx.x * 256;
    #pragma unroll
    for (int i = tid; i < 32 * FOUT; i += 256) lpool[i] = 0.f;
    int g_lo = batch[b0 / 10];
    __syncthreads();

    int gid = b0 + tid;
    if (gid < NN * 10) {
        int n = gid / 10;
        int c = gid % 10;
        unsigned int beg = rowptr[n], end = rowptr[n + 1];
        float z0 = 0.f, z1 = 0.f, z2 = 0.f, z3 = 0.f;
        const ushort4* y4 = reinterpret_cast<const ushort4*>(y);
        for (unsigned int k = beg; k < end; ++k) {
            unsigned int s = esrc[k];
            float nm = enorm[k];
            ushort4 yv = y4[s * 10 + c];
            z0 = fmaf(nm, bf16_to_f32(yv.x), z0);
            z1 = fmaf(nm, bf16_to_f32(yv.y), z1);
            z2 = fmaf(nm, bf16_to_f32(yv.z), z2);
            z3 = fmaf(nm, bf16_to_f32(yv.w), z3);
        }
        float mdi = -dinv[n];
        const float4 bv = *reinterpret_cast<const float4*>(bconv + c * 4);
        float a0 = bv.x, a1 = bv.y, a2 = bv.z, a3 = bv.w;
        const float* xr = x + (size_t)n * FIN;
        #pragma unroll 8
        for (int f = 0; f < FIN; ++f) {
            float xf = xr[f];
            const float4 wv = *reinterpret_cast<const float4*>(W0 + f * FOUT + c * 4);
            a0 = fmaf(xf, wv.x, a0); a1 = fmaf(xf, wv.y, a1);
            a2 = fmaf(xf, wv.z, a2); a3 = fmaf(xf, wv.w, a3);
        }
        float h0 = fmaxf(fmaf(mdi, z0, a0), 0.f);
        float h1 = fmaxf(fmaf(mdi, z1, a1), 0.f);
        float h2 = fmaxf(fmaf(mdi, z2, a2), 0.f);
        float h3 = fmaxf(fmaf(mdi, z3, a3), 0.f);
        float* lp = lpool + (batch[n] - g_lo) * FOUT + c * 4;
        atomicAdd(lp + 0, h0);
        atomicAdd(lp + 1, h1);
        atomicAdd(lp + 2, h2);
        atomicAdd(lp + 3, h3);
    }
    __syncthreads();
    int n_hi = (b0 + 255) / 10;
    if (n_hi > NN - 1) n_hi = NN - 1;
    int span = batch[n_hi] - g_lo + 1;
    for (int i = tid; i < span * FOUT; i += 256) {
        float v = lpool[i];
        if (v != 0.f) atomicAdd(&pooled[(size_t)g_lo * FOUT + i], v);
    }
}

// ---- pre[t][j] = pooled[t]·W_ih[j] + b_ih[j] + b_hh[j] ----
__global__ void k_pre(const float* __restrict__ pooled, const float* __restrict__ Wih,
                      const float* __restrict__ bih, const float* __restrict__ bhh,
                      float* __restrict__ pre) {
    int gid = blockIdx.x * 256 + threadIdx.x;
    if (gid >= NG * HH) return;
    int t = gid / HH;
    int j = gid % HH;
    float acc = bih[j] + bhh[j];
    #pragma unroll
    for (int f = 0; f < FOUT; ++f)
        acc = fmaf(pooled[t * FOUT + f], Wih[j * FOUT + f], acc);
    pre[gid] = acc;
}

// ---- serial scan: h_t = tanh(pre_t + W_hh h_{t-1}) ; single wave ----
__global__ void k_scan(const float* __restrict__ pre, const float* __restrict__ Whh,
                       float* __restrict__ seq) {
    __shared__ float spre[NG * HH];          // 40 KB
    int lane = threadIdx.x;
    const float4* p4 = reinterpret_cast<const float4*>(pre);
    float4* s4 = reinterpret_cast<float4*>(spre);
    #pragma unroll
    for (int j = 0; j < 40; ++j) {
        int idx = j * 64 + lane;
        if (idx < NG * HH / 4) s4[idx] = p4[idx];
    }
    float whh[HH];
    #pragma unroll
    for (int k = 0; k < HH; ++k)
        whh[k] = (lane < HH) ? Whh[lane * HH + k] : 0.f;
    __syncthreads();
    int myoff = (lane < HH) ? lane : 0;
    float h = 0.f;
    float pre_cur = spre[myoff];
    for (int t = 0; t < NG; ++t) {
        int nt = (t + 1 < NG) ? t + 1 : t;
        float pre_next = spre[nt * HH + myoff];
        float a0 = pre_cur, a1 = 0.f, a2 = 0.f, a3 = 0.f;
        #pragma unroll
        for (int k = 0; k < HH; k += 4) {
            a0 = fmaf(bcast_lane(h, k + 0), whh[k + 0], a0);
            a1 = fmaf(bcast_lane(h, k + 1), whh[k + 1], a1);
            a2 = fmaf(bcast_lane(h, k + 2), whh[k + 2], a2);
            a3 = fmaf(bcast_lane(h, k + 3), whh[k + 3], a3);
        }
        h = tanh_fast((a0 + a1) + (a2 + a3));
        if (lane < HH) seq[t * HH + lane] = h;
        pre_cur = pre_next;
    }
}

// ---- logits = seq@W_fc^T + b_fc ; log_softmax ----
__global__ void k_out(const float* __restrict__ seq, const float* __restrict__ Wfc,
                      const float* __restrict__ bfc, float* __restrict__ out) {
    int t = blockIdx.x * 64 + threadIdx.x;
    if (t >= NG) return;
    float s[HH];
    #pragma unroll
    for (int j = 0; j < HH; ++j) s[j] = seq[t * HH + j];
    float lg[NC];
    float m = -1e30f;
    #pragma unroll
    for (int c = 0; c < NC; ++c) {
        float acc = bfc[c];
        #pragma unroll
        for (int j = 0; j < HH; ++j) acc = fmaf(s[j], Wfc[c * HH + j], acc);
        lg[c] = acc;
        m = fmaxf(m, acc);
    }
    float lse = 0.f;
    #pragma unroll
    for (int c = 0; c < NC; ++c) lse += expf(lg[c] - m);
    lse = logf(lse);
    #pragma unroll
    for (int c = 0; c < NC; ++c) out[t * NC + c] = lg[c] - m - lse;
}

extern "C" void kernel_launch(void* const* d_in, const int* in_sizes, int n_in,
                              void* d_out, int out_size, void* d_ws, size_t ws_size,
                              hipStream_t stream) {
    const float* x     = (const float*)d_in[0];
    const int*   ei    = (const int*)  d_in[1];
    const float* w     = (const float*)d_in[2];
    const int*   batch = (const int*)  d_in[3];
    const float* W0    = (const float*)d_in[5];
    const float* W1    = (const float*)d_in[6];
    const float* bconv = (const float*)d_in[7];
    const float* Wih   = (const float*)d_in[8];
    const float* Whh   = (const float*)d_in[9];
    const float* bih   = (const float*)d_in[10];
    const float* bhh   = (const float*)d_in[11];
    const float* Wfc   = (const float*)d_in[12];
    const float* bfc   = (const float*)d_in[13];
    float* out = (float*)d_out;

    float*          ws     = (float*)d_ws;
    float*          degR   = ws + OFF_DEGR;
    unsigned int*   cntR   = (unsigned int*)(ws + OFF_CNTR);
    float*          pooled = ws + OFF_POOLED;
    float*          dinv   = ws + OFF_DINV;
    unsigned int*   cnt    = (unsigned int*)(ws + OFF_CNT);
    float*          pre    = ws + OFF_PRE;
    float*          seq    = ws + OFF_SEQ;
    unsigned int*   rowptr = (unsigned int*)(ws + OFF_ROWPTR);
    unsigned int*   esrc   = (unsigned int*)(ws + OFF_ESRC);
    float*          enorm  = ws + OFF_ENORM;
    unsigned short* y      = (unsigned short*)(ws + OFF_Y);

    // zero degR | cntR | pooled (contiguous)
    hipMemsetAsync(d_ws, 0, (size_t)(OFF_POOLED + NG * FOUT) * sizeof(float), stream);

    k_degcnt<<<(NE + 255) / 256, 256, 0, stream>>>(ei, w, degR, cntR);
    k_reduce<<<(NN + 255) / 256, 256, 0, stream>>>(degR, cntR, dinv, cnt);
    k_scanptr<<<1, 1024, 0, stream>>>(cnt, rowptr);
    k_y<<<(NN * 10 + 255) / 256, 256, 0, stream>>>(x, W1, dinv, y);
    k_fill<<<(NE + 255) / 256, 256, 0, stream>>>(ei, w, cnt, esrc, enorm);
    k_gather_h<<<(NN * 10 + 255) / 256, 256, 0, stream>>>(rowptr, esrc, enorm, y, x,
                                                          W0, bconv, dinv, batch, pooled);
    k_pre<<<(NG * HH + 255) / 256, 256, 0, stream>>>(pooled, Wih, bih, bhh, pre);
    k_scan<<<1, 64, 0, stream>>>(pre, Whh, seq);
    k_out<<<(NG + 63) / 64, 64, 0, stream>>>(seq, Wfc, bfc, out);
}

// Round 11
// 296.122 us; speedup vs baseline: 1.0404x; 1.0404x over previous
//
#include <hip/hip_runtime.h>
#include <math.h>

#define NN   50000
#define NE   800000
#define NG   500
#define FIN  80
#define FOUT 40
#define HH   20
#define NC   5

// -------- workspace layout (float offsets) --------
#define OFF_DEG    0               // f32[NN] -> dinv in place
#define OFF_CNT    50000           // u32[NN]
#define OFF_POOLED 100000          // f32[NG*FOUT]
#define OFF_ROWPTR 120000          // u32[NN+1] (+pad)
#define OFF_RANK   170004          // u32[NE]
#define OFF_ESRC   970004          // u32[NE]
#define OFF_ENORM  1770004         // f32[NE] (= reordered w)
#define OFF_Y      2570004         // bf16[NN*FOUT] = 4 MB (byte off %16==0)

// fast tanh: 1 - 2/(exp2(2*log2e*x)+1); exact saturation at +-inf
__device__ __forceinline__ float tanh_fast(float x) {
    float e;
    asm("v_exp_f32 %0, %1" : "=v"(e) : "v"(x * 2.8853900817779268f));
    float r;
    asm("v_rcp_f32 %0, %1" : "=v"(r) : "v"(e + 1.0f));
    return fmaf(-2.0f, r, 1.0f);
}

__device__ __forceinline__ float bcast_lane(float v, int k) {
    return __uint_as_float(__builtin_amdgcn_readlane(__float_as_uint(v), k));
}

__device__ __forceinline__ unsigned short bf16_rn(float f) {
    unsigned u = __float_as_uint(f);
    return (unsigned short)((u + 0x7fffu + ((u >> 16) & 1u)) >> 16);
}
__device__ __forceinline__ float bf16_to_f32(unsigned short h) {
    return __uint_as_float((unsigned)h << 16);
}

// ---- deg[src] += w ; rank[e] = cnt[dst]++  (rank = within-bucket position) ----
__global__ void k_degcnt(const int* __restrict__ ei, const float* __restrict__ w,
                         float* __restrict__ deg, unsigned int* __restrict__ cnt,
                         unsigned int* __restrict__ rank) {
    int e = blockIdx.x * 256 + threadIdx.x;
    if (e < NE) {
        atomicAdd(&deg[ei[e]], w[e]);
        rank[e] = atomicAdd(&cnt[ei[NE + e]], 1u);
    }
}

// ---- dinv = deg>0 ? rsqrt(deg) : 0 (in place) ----
__global__ void k_dinv(float* __restrict__ deg) {
    int n = blockIdx.x * 256 + threadIdx.x;
    if (n < NN) {
        float d = deg[n];
        deg[n] = (d > 0.f) ? rsqrtf(d) : 0.f;
    }
}

// ---- exclusive scan of cnt -> rowptr ----
__global__ void k_scanptr(const unsigned int* __restrict__ cnt, unsigned int* __restrict__ rowptr) {
    __shared__ unsigned int tot[1024];
    int tid = threadIdx.x;
    bool act = tid < 1000;
    int beg = tid * 50;
    unsigned int vals[50];
    if (act) {
        const uint2* c2 = reinterpret_cast<const uint2*>(cnt + beg);
        #pragma unroll
        for (int j = 0; j < 25; ++j) {
            uint2 v = c2[j];
            vals[j * 2 + 0] = v.x;
            vals[j * 2 + 1] = v.y;
        }
    }
    unsigned int s = 0;
    if (act) {
        #pragma unroll
        for (int j = 0; j < 50; ++j) s += vals[j];
    }
    tot[tid] = s;
    __syncthreads();
    for (int off = 1; off < 1024; off <<= 1) {
        unsigned int t = (tid >= off) ? tot[tid - off] : 0u;
        __syncthreads();
        tot[tid] += t;
        __syncthreads();
    }
    unsigned int base = (tid > 0) ? tot[tid - 1] : 0u;
    if (act) {
        #pragma unroll
        for (int j = 0; j < 50; ++j) {
            unsigned int v = vals[j];
            vals[j] = base;
            base += v;
        }
        uint2* r2 = reinterpret_cast<uint2*>(rowptr + beg);
        #pragma unroll
        for (int j = 0; j < 25; ++j)
            r2[j] = make_uint2(vals[j * 2 + 0], vals[j * 2 + 1]);
    }
    if (tid == 1023) rowptr[NN] = tot[1023];
}

// ---- y' = bf16(dinv[n] * (x @ W1)) : thread per (node, 4-col chunk) ----
__global__ void k_y(const float* __restrict__ x, const float* __restrict__ W1,
                    const float* __restrict__ dinv, unsigned short* __restrict__ y) {
    int gid = blockIdx.x * 256 + threadIdx.x;
    if (gid >= NN * 10) return;
    int n = gid / 10;
    int c = gid % 10;
    const float* xr = x + (size_t)n * FIN;
    float a0 = 0.f, a1 = 0.f, a2 = 0.f, a3 = 0.f;
    #pragma unroll 8
    for (int f = 0; f < FIN; ++f) {
        float xf = xr[f];
        const float4 wv = *reinterpret_cast<const float4*>(W1 + f * FOUT + c * 4);
        a0 = fmaf(xf, wv.x, a0); a1 = fmaf(xf, wv.y, a1);
        a2 = fmaf(xf, wv.z, a2); a3 = fmaf(xf, wv.w, a3);
    }
    float di = dinv[n];
    ushort4 o;
    o.x = bf16_rn(a0 * di); o.y = bf16_rn(a1 * di);
    o.z = bf16_rn(a2 * di); o.w = bf16_rn(a3 * di);
    *reinterpret_cast<ushort4*>(y + (size_t)gid * 4) = o;
}

// ---- fill CSR records (NO atomics): pos = rowptr[dst] + rank[e] ----
__global__ void k_fill(const int* __restrict__ ei, const float* __restrict__ w,
                       const unsigned int* __restrict__ rowptr,
                       const unsigned int* __restrict__ rank,
                       unsigned int* __restrict__ esrc, float* __restrict__ enorm) {
    int e = blockIdx.x * 256 + threadIdx.x;
    if (e >= NE) return;
    int s = ei[e];
    int d = ei[NE + e];
    unsigned int pos = rowptr[d] + rank[e];
    esrc[pos] = (unsigned int)s;
    enorm[pos] = w[e];
}

// ---- gather z = sum w*y'[src]; h = relu(x@W0 + b - dinv[n]*z);
//      per-block LDS pool accumulation, then flush to global pooled ----
__global__ void k_gather_h(const unsigned int* __restrict__ rowptr,
                           const unsigned int* __restrict__ esrc,
                           const float* __restrict__ enorm,
                           const unsigned short* __restrict__ y,
                           const float* __restrict__ x,
                           const float* __restrict__ W0,
                           const float* __restrict__ bconv,
                           const float* __restrict__ dinv,
                           const int* __restrict__ batch,
                           float* __restrict__ pooled) {
    __shared__ float lpool[32 * FOUT];
    int tid = threadIdx.x;
    int b0 = blockIdx.x * 256;
    #pragma unroll
    for (int i = tid; i < 32 * FOUT; i += 256) lpool[i] = 0.f;
    int g_lo = batch[b0 / 10];
    __syncthreads();

    int gid = b0 + tid;
    if (gid < NN * 10) {
        int n = gid / 10;
        int c = gid % 10;
        unsigned int beg = rowptr[n], end = rowptr[n + 1];
        float z0 = 0.f, z1 = 0.f, z2 = 0.f, z3 = 0.f;
        const ushort4* y4 = reinterpret_cast<const ushort4*>(y);
        for (unsigned int k = beg; k < end; ++k) {
            unsigned int s = esrc[k];
            float nm = enorm[k];
            ushort4 yv = y4[s * 10 + c];
            z0 = fmaf(nm, bf16_to_f32(yv.x), z0);
            z1 = fmaf(nm, bf16_to_f32(yv.y), z1);
            z2 = fmaf(nm, bf16_to_f32(yv.z), z2);
            z3 = fmaf(nm, bf16_to_f32(yv.w), z3);
        }
        float mdi = -dinv[n];
        const float4 bv = *reinterpret_cast<const float4*>(bconv + c * 4);
        float a0 = bv.x, a1 = bv.y, a2 = bv.z, a3 = bv.w;
        const float* xr = x + (size_t)n * FIN;
        #pragma unroll 8
        for (int f = 0; f < FIN; ++f) {
            float xf = xr[f];
            const float4 wv = *reinterpret_cast<const float4*>(W0 + f * FOUT + c * 4);
            a0 = fmaf(xf, wv.x, a0); a1 = fmaf(xf, wv.y, a1);
            a2 = fmaf(xf, wv.z, a2); a3 = fmaf(xf, wv.w, a3);
        }
        float h0 = fmaxf(fmaf(mdi, z0, a0), 0.f);
        float h1 = fmaxf(fmaf(mdi, z1, a1), 0.f);
        float h2 = fmaxf(fmaf(mdi, z2, a2), 0.f);
        float h3 = fmaxf(fmaf(mdi, z3, a3), 0.f);
        float* lp = lpool + (batch[n] - g_lo) * FOUT + c * 4;
        atomicAdd(lp + 0, h0);
        atomicAdd(lp + 1, h1);
        atomicAdd(lp + 2, h2);
        atomicAdd(lp + 3, h3);
    }
    __syncthreads();
    int n_hi = (b0 + 255) / 10;
    if (n_hi > NN - 1) n_hi = NN - 1;
    int span = batch[n_hi] - g_lo + 1;
    for (int i = tid; i < span * FOUT; i += 256) {
        float v = lpool[i];
        if (v != 0.f) atomicAdd(&pooled[(size_t)g_lo * FOUT + i], v);
    }
}

// ---- fused tail: pre (LDS) -> serial RNN scan (LDS) -> fc+log_softmax ----
// single block, 1024 threads; spre/sseq in LDS (80 KB)
__global__ void k_tail(const float* __restrict__ pooled, const float* __restrict__ Wih,
                       const float* __restrict__ bih, const float* __restrict__ bhh,
                       const float* __restrict__ Whh, const float* __restrict__ Wfc,
                       const float* __restrict__ bfc, float* __restrict__ out) {
    __shared__ float spre[NG * HH];          // 40 KB
    __shared__ float sseq[NG * HH];          // 40 KB
    int tid = threadIdx.x;

    // phase A: pre[t][j] = pooled[t]·W_ih[j] + b_ih[j] + b_hh[j]
    for (int idx = tid; idx < NG * HH; idx += 1024) {
        int t = idx / HH;
        int j = idx % HH;
        float acc = bih[j] + bhh[j];
        const float* pr = pooled + t * FOUT;
        const float* wr = Wih + j * FOUT;
        #pragma unroll
        for (int f = 0; f < FOUT; ++f) acc = fmaf(pr[f], wr[f], acc);
        spre[idx] = acc;
    }
    __syncthreads();

    // phase B: wave 0 runs the serial scan
    if (tid < 64) {
        int lane = tid;
        float whh[HH];
        #pragma unroll
        for (int k = 0; k < HH; ++k)
            whh[k] = (lane < HH) ? Whh[lane * HH + k] : 0.f;
        int myoff = (lane < HH) ? lane : 0;
        float h = 0.f;
        float pre_cur = spre[myoff];
        for (int t = 0; t < NG; ++t) {
            int nt = (t + 1 < NG) ? t + 1 : t;
            float pre_next = spre[nt * HH + myoff];
            float a0 = pre_cur, a1 = 0.f, a2 = 0.f, a3 = 0.f;
            #pragma unroll
            for (int k = 0; k < HH; k += 4) {
                a0 = fmaf(bcast_lane(h, k + 0), whh[k + 0], a0);
                a1 = fmaf(bcast_lane(h, k + 1), whh[k + 1], a1);
                a2 = fmaf(bcast_lane(h, k + 2), whh[k + 2], a2);
                a3 = fmaf(bcast_lane(h, k + 3), whh[k + 3], a3);
            }
            h = tanh_fast((a0 + a1) + (a2 + a3));
            if (lane < HH) sseq[t * HH + lane] = h;
            pre_cur = pre_next;
        }
    }
    __syncthreads();

    // phase C: logits + log_softmax, thread per graph
    if (tid < NG) {
        float s[HH];
        #pragma unroll
        for (int j = 0; j < HH; ++j) s[j] = sseq[tid * HH + j];
        float lg[NC];
        float m = -1e30f;
        #pragma unroll
        for (int c = 0; c < NC; ++c) {
            float acc = bfc[c];
            #pragma unroll
            for (int j = 0; j < HH; ++j) acc = fmaf(s[j], Wfc[c * HH + j], acc);
            lg[c] = acc;
            m = fmaxf(m, acc);
        }
        float lse = 0.f;
        #pragma unroll
        for (int c = 0; c < NC; ++c) lse += expf(lg[c] - m);
        lse = logf(lse);
        #pragma unroll
        for (int c = 0; c < NC; ++c) out[tid * NC + c] = lg[c] - m - lse;
    }
}

extern "C" void kernel_launch(void* const* d_in, const int* in_sizes, int n_in,
                              void* d_out, int out_size, void* d_ws, size_t ws_size,
                              hipStream_t stream) {
    const float* x     = (const float*)d_in[0];
    const int*   ei    = (const int*)  d_in[1];
    const float* w     = (const float*)d_in[2];
    const int*   batch = (const int*)  d_in[3];
    const float* W0    = (const float*)d_in[5];
    const float* W1    = (const float*)d_in[6];
    const float* bconv = (const float*)d_in[7];
    const float* Wih   = (const float*)d_in[8];
    const float* Whh   = (const float*)d_in[9];
    const float* bih   = (const float*)d_in[10];
    const float* bhh   = (const float*)d_in[11];
    const float* Wfc   = (const float*)d_in[12];
    const float* bfc   = (const float*)d_in[13];
    float* out = (float*)d_out;

    float*          ws     = (float*)d_ws;
    float*          deg    = ws + OFF_DEG;          // -> dinv in place
    unsigned int*   cnt    = (unsigned int*)(ws + OFF_CNT);
    float*          pooled = ws + OFF_POOLED;
    unsigned int*   rowptr = (unsigned int*)(ws + OFF_ROWPTR);
    unsigned int*   rank   = (unsigned int*)(ws + OFF_RANK);
    unsigned int*   esrc   = (unsigned int*)(ws + OFF_ESRC);
    float*          enorm  = ws + OFF_ENORM;
    unsigned short* y      = (unsigned short*)(ws + OFF_Y);

    // zero deg | cnt | pooled (contiguous, 480 KB)
    hipMemsetAsync(d_ws, 0, (size_t)(OFF_POOLED + NG * FOUT) * sizeof(float), stream);

    k_degcnt<<<(NE + 255) / 256, 256, 0, stream>>>(ei, w, deg, cnt, rank);
    k_dinv<<<(NN + 255) / 256, 256, 0, stream>>>(deg);
    k_scanptr<<<1, 1024, 0, stream>>>(cnt, rowptr);
    k_y<<<(NN * 10 + 255) / 256, 256, 0, stream>>>(x, W1, deg, y);
    k_fill<<<(NE + 255) / 256, 256, 0, stream>>>(ei, w, rowptr, rank, esrc, enorm);
    k_gather_h<<<(NN * 10 + 255) / 256, 256, 0, stream>>>(rowptr, esrc, enorm, y, x,
                                                          W0, bconv, deg, batch, pooled);
    k_tail<<<1, 1024, 0, stream>>>(pooled, Wih, bih, bhh, Whh, Wfc, bfc, out);
}

// Round 12
// 290.322 us; speedup vs baseline: 1.0612x; 1.0200x over previous
//
#include <hip/hip_runtime.h>
#include <math.h>

#define NN   50000
#define NE   800000
#define NG   500
#define FIN  80
#define FOUT 40
#define HH   20
#define NC   5

// -------- workspace layout (float offsets) --------
#define OFF_DEG    0               // f32[NN] -> dinv in place
#define OFF_CNT    50000           // u32[NN]
#define OFF_POOLED 100000          // f32[NG*FOUT]
#define OFF_SEQ    120000          // f32[NG*HH]
#define OFF_ROWPTR 130000          // u32[NN+1] (+pad)
#define OFF_RANK   180004          // u32[NE]
#define OFF_ESRC   980004          // u32[NE]
#define OFF_ENORM  1780004         // f32[NE] (= reordered w)
#define OFF_Y      2580004         // bf16[NN*FOUT] = 4 MB (byte off %8==0)

#define TWO_LOG2E 2.8853900817779268f

// tanh from PRE-SCALED input y = 2*log2e*x : 1 - 2/(exp2(y)+1)
__device__ __forceinline__ float tanh_pre(float y) {
    float e;
    asm("v_exp_f32 %0, %1" : "=v"(e) : "v"(y));
    float r;
    asm("v_rcp_f32 %0, %1" : "=v"(r) : "v"(e + 1.0f));
    return fmaf(-2.0f, r, 1.0f);
}

__device__ __forceinline__ float bcast_lane(float v, int k) {
    return __uint_as_float(__builtin_amdgcn_readlane(__float_as_uint(v), k));
}

__device__ __forceinline__ unsigned short bf16_rn(float f) {
    unsigned u = __float_as_uint(f);
    return (unsigned short)((u + 0x7fffu + ((u >> 16) & 1u)) >> 16);
}
__device__ __forceinline__ float bf16_to_f32(unsigned short h) {
    return __uint_as_float((unsigned)h << 16);
}

// ---- deg[src] += w ; rank[e] = cnt[dst]++ ----
__global__ void k_degcnt(const int* __restrict__ ei, const float* __restrict__ w,
                         float* __restrict__ deg, unsigned int* __restrict__ cnt,
                         unsigned int* __restrict__ rank) {
    int e = blockIdx.x * 256 + threadIdx.x;
    if (e < NE) {
        atomicAdd(&deg[ei[e]], w[e]);
        rank[e] = atomicAdd(&cnt[ei[NE + e]], 1u);
    }
}

// ---- dinv = deg>0 ? rsqrt(deg) : 0 (in place) ----
__global__ void k_dinv(float* __restrict__ deg) {
    int n = blockIdx.x * 256 + threadIdx.x;
    if (n < NN) {
        float d = deg[n];
        deg[n] = (d > 0.f) ? rsqrtf(d) : 0.f;
    }
}

// ---- exclusive scan of cnt -> rowptr ----
__global__ void k_scanptr(const unsigned int* __restrict__ cnt, unsigned int* __restrict__ rowptr) {
    __shared__ unsigned int tot[1024];
    int tid = threadIdx.x;
    bool act = tid < 1000;
    int beg = tid * 50;
    unsigned int vals[50];
    if (act) {
        const uint2* c2 = reinterpret_cast<const uint2*>(cnt + beg);
        #pragma unroll
        for (int j = 0; j < 25; ++j) {
            uint2 v = c2[j];
            vals[j * 2 + 0] = v.x;
            vals[j * 2 + 1] = v.y;
        }
    }
    unsigned int s = 0;
    if (act) {
        #pragma unroll
        for (int j = 0; j < 50; ++j) s += vals[j];
    }
    tot[tid] = s;
    __syncthreads();
    for (int off = 1; off < 1024; off <<= 1) {
        unsigned int t = (tid >= off) ? tot[tid - off] : 0u;
        __syncthreads();
        tot[tid] += t;
        __syncthreads();
    }
    unsigned int base = (tid > 0) ? tot[tid - 1] : 0u;
    if (act) {
        #pragma unroll
        for (int j = 0; j < 50; ++j) {
            unsigned int v = vals[j];
            vals[j] = base;
            base += v;
        }
        uint2* r2 = reinterpret_cast<uint2*>(rowptr + beg);
        #pragma unroll
        for (int j = 0; j < 25; ++j)
            r2[j] = make_uint2(vals[j * 2 + 0], vals[j * 2 + 1]);
    }
    if (tid == 1023) rowptr[NN] = tot[1023];
}

// ---- y' = bf16(dinv[n] * (x @ W1)) ----
__global__ void k_y(const float* __restrict__ x, const float* __restrict__ W1,
                    const float* __restrict__ dinv, unsigned short* __restrict__ y) {
    int gid = blockIdx.x * 256 + threadIdx.x;
    if (gid >= NN * 10) return;
    int n = gid / 10;
    int c = gid % 10;
    const float* xr = x + (size_t)n * FIN;
    float a0 = 0.f, a1 = 0.f, a2 = 0.f, a3 = 0.f;
    #pragma unroll 8
    for (int f = 0; f < FIN; ++f) {
        float xf = xr[f];
        const float4 wv = *reinterpret_cast<const float4*>(W1 + f * FOUT + c * 4);
        a0 = fmaf(xf, wv.x, a0); a1 = fmaf(xf, wv.y, a1);
        a2 = fmaf(xf, wv.z, a2); a3 = fmaf(xf, wv.w, a3);
    }
    float di = dinv[n];
    ushort4 o;
    o.x = bf16_rn(a0 * di); o.y = bf16_rn(a1 * di);
    o.z = bf16_rn(a2 * di); o.w = bf16_rn(a3 * di);
    *reinterpret_cast<ushort4*>(y + (size_t)gid * 4) = o;
}

// ---- fill CSR records (NO atomics): pos = rowptr[dst] + rank[e] ----
__global__ void k_fill(const int* __restrict__ ei, const float* __restrict__ w,
                       const unsigned int* __restrict__ rowptr,
                       const unsigned int* __restrict__ rank,
                       unsigned int* __restrict__ esrc, float* __restrict__ enorm) {
    int e = blockIdx.x * 256 + threadIdx.x;
    if (e >= NE) return;
    int s = ei[e];
    int d = ei[NE + e];
    unsigned int pos = rowptr[d] + rank[e];
    esrc[pos] = (unsigned int)s;
    enorm[pos] = w[e];
}

// ---- gather z = sum w*y'[src]; h = relu(x@W0 + b - dinv[n]*z); LDS pool ----
__global__ void k_gather_h(const unsigned int* __restrict__ rowptr,
                           const unsigned int* __restrict__ esrc,
                           const float* __restrict__ enorm,
                           const unsigned short* __restrict__ y,
                           const float* __restrict__ x,
                           const float* __restrict__ W0,
                           const float* __restrict__ bconv,
                           const float* __restrict__ dinv,
                           const int* __restrict__ batch,
                           float* __restrict__ pooled) {
    __shared__ float lpool[32 * FOUT];
    int tid = threadIdx.x;
    int b0 = blockIdx.x * 256;
    #pragma unroll
    for (int i = tid; i < 32 * FOUT; i += 256) lpool[i] = 0.f;
    int g_lo = batch[b0 / 10];
    __syncthreads();

    int gid = b0 + tid;
    if (gid < NN * 10) {
        int n = gid / 10;
        int c = gid % 10;
        unsigned int beg = rowptr[n], end = rowptr[n + 1];
        float z0 = 0.f, z1 = 0.f, z2 = 0.f, z3 = 0.f;
        const ushort4* y4 = reinterpret_cast<const ushort4*>(y);
        for (unsigned int k = beg; k < end; ++k) {
            unsigned int s = esrc[k];
            float nm = enorm[k];
            ushort4 yv = y4[s * 10 + c];
            z0 = fmaf(nm, bf16_to_f32(yv.x), z0);
            z1 = fmaf(nm, bf16_to_f32(yv.y), z1);
            z2 = fmaf(nm, bf16_to_f32(yv.z), z2);
            z3 = fmaf(nm, bf16_to_f32(yv.w), z3);
        }
        float mdi = -dinv[n];
        const float4 bv = *reinterpret_cast<const float4*>(bconv + c * 4);
        float a0 = bv.x, a1 = bv.y, a2 = bv.z, a3 = bv.w;
        const float* xr = x + (size_t)n * FIN;
        #pragma unroll 8
        for (int f = 0; f < FIN; ++f) {
            float xf = xr[f];
            const float4 wv = *reinterpret_cast<const float4*>(W0 + f * FOUT + c * 4);
            a0 = fmaf(xf, wv.x, a0); a1 = fmaf(xf, wv.y, a1);
            a2 = fmaf(xf, wv.z, a2); a3 = fmaf(xf, wv.w, a3);
        }
        float h0 = fmaxf(fmaf(mdi, z0, a0), 0.f);
        float h1 = fmaxf(fmaf(mdi, z1, a1), 0.f);
        float h2 = fmaxf(fmaf(mdi, z2, a2), 0.f);
        float h3 = fmaxf(fmaf(mdi, z3, a3), 0.f);
        float* lp = lpool + (batch[n] - g_lo) * FOUT + c * 4;
        atomicAdd(lp + 0, h0);
        atomicAdd(lp + 1, h1);
        atomicAdd(lp + 2, h2);
        atomicAdd(lp + 3, h3);
    }
    __syncthreads();
    int n_hi = (b0 + 255) / 10;
    if (n_hi > NN - 1) n_hi = NN - 1;
    int span = batch[n_hi] - g_lo + 1;
    for (int i = tid; i < span * FOUT; i += 256) {
        float v = lpool[i];
        if (v != 0.f) atomicAdd(&pooled[(size_t)g_lo * FOUT + i], v);
    }
}

// ---- fused tail: pre(LDS, pre-scaled) -> scan (global seq) -> fc+log_softmax ----
__global__ void k_tail(const float* __restrict__ pooled, const float* __restrict__ Wih,
                       const float* __restrict__ bih, const float* __restrict__ bhh,
                       const float* __restrict__ Whh, const float* __restrict__ Wfc,
                       const float* __restrict__ bfc, float* __restrict__ seq,
                       float* __restrict__ out) {
    __shared__ float spre[NG * HH];          // 40 KB, pre-scaled by 2*log2e
    int tid = threadIdx.x;

    // phase A: spre[t][j] = 2log2e * (pooled[t]·W_ih[j] + b_ih[j] + b_hh[j])
    for (int idx = tid; idx < NG * HH; idx += 1024) {
        int t = idx / HH;
        int j = idx % HH;
        float acc = bih[j] + bhh[j];
        const float* pr = pooled + t * FOUT;
        const float* wr = Wih + j * FOUT;
        #pragma unroll
        for (int f = 0; f < FOUT; ++f) acc = fmaf(pr[f], wr[f], acc);
        spre[idx] = acc * TWO_LOG2E;
    }
    __syncthreads();

    // phase B: wave 0 runs the serial scan; seq written to GLOBAL (off the
    // lgkmcnt chain); all 20 readlanes batched before the FMA tree.
    if (tid < 64) {
        int lane = tid;
        float whh[HH];
        #pragma unroll
        for (int k = 0; k < HH; ++k)
            whh[k] = (lane < HH) ? Whh[lane * HH + k] * TWO_LOG2E : 0.f;
        int myoff = (lane < HH) ? lane : 0;
        float h = 0.f;
        float pre_cur = spre[myoff];
        for (int t = 0; t < NG; ++t) {
            int nt = (t + 1 < NG) ? t + 1 : t;
            float pre_next = spre[nt * HH + myoff];
            float hv[HH];
            #pragma unroll
            for (int k = 0; k < HH; ++k) hv[k] = bcast_lane(h, k);
            float a0 = pre_cur, a1 = 0.f, a2 = 0.f, a3 = 0.f;
            #pragma unroll
            for (int k = 0; k < HH; k += 4) {
                a0 = fmaf(hv[k + 0], whh[k + 0], a0);
                a1 = fmaf(hv[k + 1], whh[k + 1], a1);
                a2 = fmaf(hv[k + 2], whh[k + 2], a2);
                a3 = fmaf(hv[k + 3], whh[k + 3], a3);
            }
            h = tanh_pre((a0 + a1) + (a2 + a3));
            if (lane < HH) seq[t * HH + lane] = h;
            pre_cur = pre_next;
        }
    }
    __syncthreads();   // fences global within block

    // phase C: logits + log_softmax, thread per graph (reads global seq)
    if (tid < NG) {
        float s[HH];
        #pragma unroll
        for (int j = 0; j < HH; ++j) s[j] = seq[tid * HH + j];
        float lg[NC];
        float m = -1e30f;
        #pragma unroll
        for (int c = 0; c < NC; ++c) {
            float acc = bfc[c];
            #pragma unroll
            for (int j = 0; j < HH; ++j) acc = fmaf(s[j], Wfc[c * HH + j], acc);
            lg[c] = acc;
            m = fmaxf(m, acc);
        }
        float lse = 0.f;
        #pragma unroll
        for (int c = 0; c < NC; ++c) lse += expf(lg[c] - m);
        lse = logf(lse);
        #pragma unroll
        for (int c = 0; c < NC; ++c) out[tid * NC + c] = lg[c] - m - lse;
    }
}

extern "C" void kernel_launch(void* const* d_in, const int* in_sizes, int n_in,
                              void* d_out, int out_size, void* d_ws, size_t ws_size,
                              hipStream_t stream) {
    const float* x     = (const float*)d_in[0];
    const int*   ei    = (const int*)  d_in[1];
    const float* w     = (const float*)d_in[2];
    const int*   batch = (const int*)  d_in[3];
    const float* W0    = (const float*)d_in[5];
    const float* W1    = (const float*)d_in[6];
    const float* bconv = (const float*)d_in[7];
    const float* Wih   = (const float*)d_in[8];
    const float* Whh   = (const float*)d_in[9];
    const float* bih   = (const float*)d_in[10];
    const float* bhh   = (const float*)d_in[11];
    const float* Wfc   = (const float*)d_in[12];
    const float* bfc   = (const float*)d_in[13];
    float* out = (float*)d_out;

    float*          ws     = (float*)d_ws;
    float*          deg    = ws + OFF_DEG;          // -> dinv in place
    unsigned int*   cnt    = (unsigned int*)(ws + OFF_CNT);
    float*          pooled = ws + OFF_POOLED;
    float*          seq    = ws + OFF_SEQ;
    unsigned int*   rowptr = (unsigned int*)(ws + OFF_ROWPTR);
    unsigned int*   rank   = (unsigned int*)(ws + OFF_RANK);
    unsigned int*   esrc   = (unsigned int*)(ws + OFF_ESRC);
    float*          enorm  = ws + OFF_ENORM;
    unsigned short* y      = (unsigned short*)(ws + OFF_Y);

    // zero deg | cnt | pooled (contiguous, 480 KB)
    hipMemsetAsync(d_ws, 0, (size_t)(OFF_POOLED + NG * FOUT) * sizeof(float), stream);

    k_degcnt<<<(NE + 255) / 256, 256, 0, stream>>>(ei, w, deg, cnt, rank);
    k_dinv<<<(NN + 255) / 256, 256, 0, stream>>>(deg);
    k_scanptr<<<1, 1024, 0, stream>>>(cnt, rowptr);
    k_y<<<(NN * 10 + 255) / 256, 256, 0, stream>>>(x, W1, deg, y);
    k_fill<<<(NE + 255) / 256, 256, 0, stream>>>(ei, w, rowptr, rank, esrc, enorm);
    k_gather_h<<<(NN * 10 + 255) / 256, 256, 0, stream>>>(rowptr, esrc, enorm, y, x,
                                                          W0, bconv, deg, batch, pooled);
    k_tail<<<1, 1024, 0, stream>>>(pooled, Wih, bih, bhh, Whh, Wfc, bfc, seq, out);
}